// Round 9
// baseline (3058.592 us; speedup 1.0000x reference)
//
#include <hip/hip_runtime.h>
#include <math.h>

#define NB 16
#define NH 64
#define NPTS 2048
#define NEIGHS 20
#define KSEL 512
#define EPSV 1e-5f
#define NINF -3.0e38f

typedef unsigned long long ull;

// output layout (floats), reference return order
#define OFF_SEQ 0
#define OFF_VAL (NB*NH*KSEL)            // 524288
#define OFF_IDX (OFF_VAL + NB*KSEL)     // 532480
#define OFF_RET (OFF_IDX + NB*KSEL)     // 540672
#define OFF_XST (OFF_RET + NB*2*NPTS)   // 606208
#define OFF_XO  (OFF_XST + NB*3*KSEL)   // 630784

__device__ __forceinline__ bool better(float av, int ai, float bv, int bi) {
  return (av > bv) || (av == bv && ai < bi);
}

// exact (val desc, idx asc) total order as one u64: bigger u64 = better
__device__ __forceinline__ ull packkey(float v, int ci) {
  unsigned u = __float_as_uint(v);
  u = (u & 0x80000000u) ? ~u : (u | 0x80000000u);
  return ((ull)u << 32) | (unsigned)(~ci);
}

// K1: pts = relu(bn1(Wfc@seq1 + bfc)), plus x2, G1, G2, and ptsT [b][c][n].
// (unchanged from the passing R8 kernel)
__global__ __launch_bounds__(256) void k_fc(const float* __restrict__ seq1,
                                            const float* __restrict__ Wfc,
                                            const float* __restrict__ bfc,
                                            const float* __restrict__ b1g,
                                            const float* __restrict__ b1b,
                                            const float* __restrict__ b1m,
                                            const float* __restrict__ b1v,
                                            const float* __restrict__ Wec,
                                            float* __restrict__ pts,
                                            float* __restrict__ ptsT,
                                            float* __restrict__ G1,
                                            float* __restrict__ G2,
                                            float* __restrict__ x2) {
  const int b = blockIdx.y, n0 = blockIdx.x * 64;
  const int tid = threadIdx.x, l = tid & 63, w = tid >> 6;
  const int n = n0 + l;
  __shared__ float ptL[64*65];
  const float* sq = seq1 + (size_t)b*NH*NPTS + n;
  float x[64];
  #pragma unroll
  for (int c = 0; c < 64; ++c) x[c] = sq[(size_t)c*NPTS];

  for (int oo = 0; oo < 16; ++oo) {
    const int o = w*16 + oo;
    float acc = 0.f;
    const float* ar = Wfc + o*64;
    #pragma unroll
    for (int c = 0; c < 64; c += 4) {
      float4 a4 = *(const float4*)(ar + c);
      acc = fmaf(a4.x, x[c],   acc);
      acc = fmaf(a4.y, x[c+1], acc);
      acc = fmaf(a4.z, x[c+2], acc);
      acc = fmaf(a4.w, x[c+3], acc);
    }
    float s1 = b1g[o] / sqrtf(b1v[o] + EPSV);
    float y  = (acc + bfc[o] - b1m[o]) * s1 + b1b[o];
    ptL[l*65 + o] = fmaxf(y, 0.f);
  }
  __syncthreads();
  float pt[64];
  #pragma unroll
  for (int c = 0; c < 64; ++c) pt[c] = ptL[l*65 + c];
  if (w == 0) {
    float s2 = 0.f;
    #pragma unroll
    for (int c = 0; c < 64; ++c) s2 = fmaf(pt[c], pt[c], s2);
    x2[(size_t)b*NPTS + n] = s2;
  }
  const size_t base = ((size_t)b*NPTS + n0)*NH;
  for (int t = w*16; t < w*16 + 16; ++t) pts[base + t*64 + l] = ptL[t*65 + l];
  for (int c = w*16; c < w*16 + 16; ++c)
    ptsT[((size_t)b*NH + c)*NPTS + n] = ptL[l*65 + c];
  __syncthreads();

  for (int oo = 0; oo < 16; ++oo) {
    const int o = w*16 + oo;
    const float* w1 = Wec + o*128;
    float a1 = 0.f;
    #pragma unroll
    for (int c = 0; c < 64; c += 4) {
      float4 u = *(const float4*)(w1 + c);
      a1 = fmaf(u.x, pt[c],   a1); a1 = fmaf(u.y, pt[c+1], a1);
      a1 = fmaf(u.z, pt[c+2], a1); a1 = fmaf(u.w, pt[c+3], a1);
    }
    ptL[l*65 + o] = a1;
  }
  __syncthreads();
  for (int t = w*16; t < w*16 + 16; ++t) G1[base + t*64 + l] = ptL[t*65 + l];
  __syncthreads();

  for (int oo = 0; oo < 16; ++oo) {
    const int o = w*16 + oo;
    const float* w2 = Wec + o*128 + 64;
    float a2 = 0.f;
    #pragma unroll
    for (int c = 0; c < 64; c += 4) {
      float4 v = *(const float4*)(w2 + c);
      a2 = fmaf(v.x, pt[c],   a2); a2 = fmaf(v.y, pt[c+1], a2);
      a2 = fmaf(v.z, pt[c+2], a2); a2 = fmaf(v.w, pt[c+3], a2);
    }
    ptL[l*65 + o] = a2;
  }
  __syncthreads();
  for (int t = w*16; t < w*16 + 16; ++t) G2[base + t*64 + l] = ptL[t*65 + l];
}

// ---- K2 helpers ----
#define FMA4(A, s, F) { (A).x = fmaf((s),(F).x,(A).x); (A).y = fmaf((s),(F).y,(A).y); \
                        (A).z = fmaf((s),(F).z,(A).z); (A).w = fmaf((s),(F).w,(A).w); }

// branchless sorted-4 (desc) insert of u64 key
#define INS4(CAND) { ull c_=(CAND); \
  { bool b_=c_>K0; ull n_=b_?c_:K0; ull o_=K0; c_=b_?o_:c_; K0=n_; } \
  { bool b_=c_>K1; ull n_=b_?c_:K1; ull o_=K1; c_=b_?o_:c_; K1=n_; } \
  { bool b_=c_>K2; ull n_=b_?c_:K2; ull o_=K2; c_=b_?o_:c_; K2=n_; } \
  { bool b_=c_>K3; ull n_=b_?c_:K3; c_=0;       K3=n_; } }

// build sorted-4 for one row's 16 lane-local candidates, dump to LDS
// dump layout [e(4)][row(16)][cell(128)] u64 (lane-consecutive writes)
#define BUILDROW(T0,T1,T2,T3,RI) { \
  ull K0=0,K1=0,K2=0,K3=0; \
  INS4(packkey(fmaf(2.f,(T0).x,-x0.x), cbase+0))   INS4(packkey(fmaf(2.f,(T0).y,-x0.y), cbase+1)) \
  INS4(packkey(fmaf(2.f,(T0).z,-x0.z), cbase+2))   INS4(packkey(fmaf(2.f,(T0).w,-x0.w), cbase+3)) \
  INS4(packkey(fmaf(2.f,(T1).x,-x1.x), cbase+256)) INS4(packkey(fmaf(2.f,(T1).y,-x1.y), cbase+257)) \
  INS4(packkey(fmaf(2.f,(T1).z,-x1.z), cbase+258)) INS4(packkey(fmaf(2.f,(T1).w,-x1.w), cbase+259)) \
  INS4(packkey(fmaf(2.f,(T2).x,-x2q.x), cbase+512)) INS4(packkey(fmaf(2.f,(T2).y,-x2q.y), cbase+513)) \
  INS4(packkey(fmaf(2.f,(T2).z,-x2q.z), cbase+514)) INS4(packkey(fmaf(2.f,(T2).w,-x2q.w), cbase+515)) \
  INS4(packkey(fmaf(2.f,(T3).x,-x3.x), cbase+768)) INS4(packkey(fmaf(2.f,(T3).y,-x3.y), cbase+769)) \
  INS4(packkey(fmaf(2.f,(T3).z,-x3.z), cbase+770)) INS4(packkey(fmaf(2.f,(T3).w,-x3.w), cbase+771)) \
  { int row_ = g*4+(RI), cell_ = h*64+l; \
    dumpS[(0*16+row_)*128 + cell_] = K0; \
    dumpS[(1*16+row_)*128 + cell_] = K1; \
    dumpS[(2*16+row_)*128 + cell_] = K2; \
    dumpS[(3*16+row_)*128 + cell_] = K3; } }

#define INS20U(CAND) { ull c_=(CAND); \
  _Pragma("unroll") \
  for (int k_=0; k_<20; ++k_) { bool b_=c_>L[k_]; ull n_=b_?c_:L[k_]; ull o_=L[k_]; c_=b_?o_:c_; L[k_]=n_; } }

// K2: 8 waves x (4 rows, 16 cols/lane) GEMM (= R8), then LDS-dump selection:
// per-(lane,row) sorted-4 u64 -> dump -> one lane per row serial ins20 merge
// (no shuffles). Airtight fallback: if any cell's 4th-best beats the final
// 20th, the block brute-force recomputes that row with the identical fmaf
// chain and re-selects exactly (P ~ 5e-5 per row).
__global__ __launch_bounds__(512) void k_knn(const float* __restrict__ pts,
                                             const float* __restrict__ ptsT,
                                             const float* __restrict__ x2,
                                             int* __restrict__ nidx) {
  const int lin = blockIdx.x;
  const int b  = ((lin & 7) << 1) | ((lin >> 3) & 1);  // XCD-local batches
  const int rg = lin >> 4;                              // 0..127
  const int tid = threadIdx.x, w = tid >> 6, l = tid & 63;
  const int g = w >> 1, h = w & 1;     // row group 0..3, col half 0..1
  const int r0 = rg*16;

  __shared__ __align__(16) unsigned char smem[65536 + 4096 + 64];
  float* colB0 = (float*)smem;                 // [8192] buf 0
  float* colB1 = (float*)(smem + 32768);       // [8192] buf 1
  ull*   dumpS = (ull*)smem;                   // [4][16][128] (overlays colB)
  ull*   kbuf  = (ull*)smem;                   // [2048] fallback (overlays)
  float* rowS  = (float*)(smem + 65536);       // [16][64]
  int*   flagS = (int*)(smem + 65536 + 4096);  // [16]

  const float* Tb = ptsT + (size_t)b*NH*NPTS;

  // stage 16 row vectors
  if (tid < 256) {
    int rr = tid >> 4, c4 = (tid & 15) * 4;
    *(float4*)&rowS[rr*64 + c4] =
        *(const float4*)(pts + ((size_t)b*NPTS + r0 + rr)*NH + c4);
  }
  // stage chunk 0
  #pragma unroll
  for (int s = 0; s < 4; ++s) {
    float4 v = *(const float4*)(Tb + (w*4+s)*256 + l*4);
    *(float4*)&colB0[(w*4+s)*256 + l*4] = v;
  }
  __syncthreads();

  float4 A00={0,0,0,0},A01={0,0,0,0},A02={0,0,0,0},A03={0,0,0,0};
  float4 A10={0,0,0,0},A11={0,0,0,0},A12={0,0,0,0},A13={0,0,0,0};
  float4 A20={0,0,0,0},A21={0,0,0,0},A22={0,0,0,0},A23={0,0,0,0};
  float4 A30={0,0,0,0},A31={0,0,0,0},A32={0,0,0,0},A33={0,0,0,0};

  #pragma unroll 1
  for (int t = 0; t < 16; ++t) {
    float4 st0, st1, st2, st3;
    if (t < 15) {   // T14 issue-early
      const float* src = Tb + (size_t)(t+1)*8192 + w*1024 + l*4;
      st0 = *(const float4*)(src);
      st1 = *(const float4*)(src + 256);
      st2 = *(const float4*)(src + 512);
      st3 = *(const float4*)(src + 768);
    }
    const float* cb = ((t & 1) ? colB1 : colB0) + h*1024 + l*4;
    const float* rs = &rowS[(g*4)*64 + t*4];
    #pragma unroll
    for (int k = 0; k < 4; ++k) {
      float4 f0 = *(const float4*)(cb + k*2048);
      float4 f1 = *(const float4*)(cb + k*2048 + 256);
      float4 f2 = *(const float4*)(cb + k*2048 + 512);
      float4 f3 = *(const float4*)(cb + k*2048 + 768);
      float r0k = rs[k], r1k = rs[64 + k], r2k = rs[128 + k], r3k = rs[192 + k];
      FMA4(A00,r0k,f0) FMA4(A01,r0k,f1) FMA4(A02,r0k,f2) FMA4(A03,r0k,f3)
      FMA4(A10,r1k,f0) FMA4(A11,r1k,f1) FMA4(A12,r1k,f2) FMA4(A13,r1k,f3)
      FMA4(A20,r2k,f0) FMA4(A21,r2k,f1) FMA4(A22,r2k,f2) FMA4(A23,r2k,f3)
      FMA4(A30,r3k,f0) FMA4(A31,r3k,f1) FMA4(A32,r3k,f2) FMA4(A33,r3k,f3)
    }
    if (t < 15) {   // write-late
      float* d = ((t & 1) ? colB0 : colB1) + w*1024 + l*4;
      *(float4*)(d)       = st0;
      *(float4*)(d + 256) = st1;
      *(float4*)(d + 512) = st2;
      *(float4*)(d + 768) = st3;
    }
    __syncthreads();
  }
  // colB dead from here (barrier above) — dumpS may overlay it

  const int cbase = h*1024 + l*4;
  const float* x2b = x2 + (size_t)b*NPTS + cbase;
  float4 x0  = *(const float4*)(x2b);
  float4 x1  = *(const float4*)(x2b + 256);
  float4 x2q = *(const float4*)(x2b + 512);
  float4 x3  = *(const float4*)(x2b + 768);

  BUILDROW(A00,A01,A02,A03,0)
  BUILDROW(A10,A11,A12,A13,1)
  BUILDROW(A20,A21,A22,A23,2)
  BUILDROW(A30,A31,A32,A33,3)
  __syncthreads();

  // merge: wave w, lanes 0..1 -> row = w*2 + l; serial ins20 over 512 entries
  if (l < 2) {
    const int row = w*2 + l;
    ull L[20];
    #pragma unroll
    for (int k = 0; k < 20; ++k) L[k] = 0;
    ull maxB = 0;
    #pragma unroll 1
    for (int cell = 0; cell < 128; ++cell) {
      int cs = (l*64 + cell) & 127;
      ull e0 = dumpS[(0*16+row)*128 + cs];
      ull e1 = dumpS[(1*16+row)*128 + cs];
      ull e2 = dumpS[(2*16+row)*128 + cs];
      ull e3 = dumpS[(3*16+row)*128 + cs];
      maxB = (e3 > maxB) ? e3 : maxB;
      if (e0 > L[19]) { INS20U(e0) }
      if (e1 > L[19]) { INS20U(e1) }
      if (e2 > L[19]) { INS20U(e2) }
      if (e3 > L[19]) { INS20U(e3) }
    }
    bool bad = (maxB > L[19]);
    flagS[row] = bad ? 1 : 0;
    if (!bad) {
      int* dst = nidx + ((size_t)b*NPTS + r0 + row)*NEIGHS;
      #pragma unroll
      for (int k = 0; k < 20; ++k) dst[k] = (int)(~(unsigned)(L[k] & 0xffffffffULL)) & 0x7fffffff;
    }
  }
  __syncthreads();

  // rare airtight fallback: block-wide exact recompute of flagged rows
  #pragma unroll 1
  for (int r = 0; r < 16; ++r) {
    if (flagS[r]) {
      // recompute the row's 2048 keys with the IDENTICAL fmaf chain
      #pragma unroll 1
      for (int col = tid; col < NPTS; col += 512) {
        float acc = 0.f;
        const float* Tc = Tb + col;
        #pragma unroll
        for (int c = 0; c < 64; ++c)
          acc = fmaf(rowS[r*64 + c], Tc[(size_t)c*NPTS], acc);
        float key = fmaf(2.f, acc, -x2[(size_t)b*NPTS + col]);
        kbuf[col] = packkey(key, col);
      }
      __syncthreads();
      if (tid == 0) {
        ull L[20];
        #pragma unroll
        for (int k = 0; k < 20; ++k) L[k] = 0;
        #pragma unroll 1
        for (int col = 0; col < NPTS; ++col) {
          ull e = kbuf[col];
          if (e > L[19]) { INS20U(e) }
        }
        int* dst = nidx + ((size_t)b*NPTS + r0 + r)*NEIGHS;
        #pragma unroll
        for (int k = 0; k < 20; ++k) dst[k] = (int)(~(unsigned)(L[k] & 0xffffffffULL)) & 0x7fffffff;
      }
      __syncthreads();
    }
  }
}

// K3: per-point neighbor max -> X -> v = Wb@X -> sc1/sc2/ret. (unchanged)
__global__ __launch_bounds__(256) void k_score(const float* __restrict__ pts,
    const float* __restrict__ G1, const float* __restrict__ G2,
    const int* __restrict__ nidx, const int* __restrict__ perm,
    const float* __restrict__ Wb,
    const float* __restrict__ b2g, const float* __restrict__ b2b,
    const float* __restrict__ b2m, const float* __restrict__ b2v,
    const float* __restrict__ bb,
    float* __restrict__ sc1w, float* __restrict__ out) {
  const int b = blockIdx.y;
  const int n0 = blockIdx.x * 16;
  const int tid = threadIdx.x, l = tid & 63, w = tid >> 6;
  __shared__ float WbS[64*65];
  for (int i = tid; i < 64*64; i += 256) WbS[(i >> 6)*65 + (i & 63)] = Wb[i];
  __syncthreads();
  const float sc2v = b2g[l] / sqrtf(b2v[l] + EPSV);
  const float mean2 = b2m[l], beta2 = b2b[l];
  const float bbv = bb[0];
  const float* G1b = G1 + (size_t)b*NPTS*NH;
  for (int it = 0; it < 4; ++it) {
    const int n = n0 + it*4 + w;
    const size_t ro = (size_t)b*NPTS*NH + (size_t)n*NH;
    const float base = G2[ro + l] - G1[ro + l];
    const int* nb = nidx + ((size_t)b*NPTS + n)*NEIGHS;
    float mx = NINF;
    #pragma unroll
    for (int k = 0; k < NEIGHS; ++k) {
      int m = nb[k];
      float val = G1b[(size_t)m*NH + l] + base;
      float y = (val - mean2) * sc2v + beta2;
      y = (y >= 0.f) ? y : 0.2f*y;
      mx = fmaxf(mx, y);
    }
    float X = 1.f / (1.f + expf(-mx));
    double v = 0.0;
    #pragma unroll
    for (int d = 0; d < 64; ++d) {
      float xd = __shfl(X, d, 64);
      v += (double)WbS[l*65 + d] * (double)xd;
    }
    float p1 = pts[ro + l];
    int pn = perm[n];
    float p2 = pts[(size_t)b*NPTS*NH + (size_t)pn*NH + l];
    double s1 = (double)p1 * v;
    double s2 = (double)p2 * v;
    #pragma unroll
    for (int off = 32; off > 0; off >>= 1) {
      s1 += __shfl_xor(s1, off, 64);
      s2 += __shfl_xor(s2, off, 64);
    }
    if (l == 0) {
      float r1 = (float)(s1 + (double)bbv);
      float r2 = (float)(s2 + (double)bbv);
      sc1w[(size_t)b*NPTS + n] = r1;
      out[OFF_RET + (size_t)b*2*NPTS + n] = r1;
      out[OFF_RET + (size_t)b*2*NPTS + NPTS + n] = r2;
    }
  }
}

// K4: per-batch exact top-512 via u64 bitonic sort + gathers. (unchanged)
__global__ __launch_bounds__(256) void k_select(const float* __restrict__ sc1w,
    const float* __restrict__ seq1, const float* __restrict__ xyz,
    float* __restrict__ out) {
  const int b = blockIdx.x, tid = threadIdx.x;
  __shared__ unsigned long long keys[NPTS];
  __shared__ float valS[KSEL];
  __shared__ int idxS[KSEL];
  for (int i = tid; i < NPTS; i += 256) {
    float f = sc1w[(size_t)b*NPTS + i];
    unsigned u = __float_as_uint(f);
    u = (u & 0x80000000u) ? ~u : (u | 0x80000000u);
    keys[i] = ((unsigned long long)(~u) << 32) | (unsigned)i;
  }
  __syncthreads();
  for (int k = 2; k <= NPTS; k <<= 1) {
    for (int j = k >> 1; j > 0; j >>= 1) {
      for (int i = tid; i < NPTS; i += 256) {
        int l2 = i ^ j;
        if (l2 > i) {
          unsigned long long a = keys[i], c = keys[l2];
          bool up = ((i & k) == 0);
          if ((a > c) == up) { keys[i] = c; keys[l2] = a; }
        }
      }
      __syncthreads();
    }
  }
  for (int i = tid; i < KSEL; i += 256) {
    unsigned long long key = keys[i];
    int sidx = (int)(key & 0xffffffffULL);
    unsigned u = ~(unsigned)(key >> 32);
    unsigned fb = (u & 0x80000000u) ? (u & 0x7fffffffu) : ~u;
    float f = __uint_as_float(fb);
    float val = 1.f / (1.f + expf(-f));
    valS[i] = val; idxS[i] = sidx;
    out[OFF_VAL + (size_t)b*KSEL + i] = val;
    out[OFF_IDX + (size_t)b*KSEL + i] = (float)sidx;
  }
  __syncthreads();
  for (int t = tid; t < NH*KSEL; t += 256) {
    int c = t >> 9, i = t & (KSEL-1);
    float sv = seq1[((size_t)b*NH + c)*NPTS + idxS[i]];
    out[OFF_SEQ + (((size_t)b*NH + c) << 9) + i] = sv * valS[i];
  }
  for (int t = tid; t < 3*KSEL; t += 256) {
    int c = t >> 9, i = t & (KSEL-1);
    float xv = xyz[((size_t)b*3 + c)*NPTS + idxS[i]];
    out[OFF_XST + (((size_t)b*3 + c) << 9) + i] = xv;
    out[OFF_XO  + (((size_t)b*3 + c) << 9) + i] = xv * valS[i];
  }
}

extern "C" void kernel_launch(void* const* d_in, const int* in_sizes, int n_in,
                              void* d_out, int out_size, void* d_ws, size_t ws_size,
                              hipStream_t stream) {
  const float* xyz  = (const float*)d_in[0];
  const float* seq1 = (const float*)d_in[1];
  const int*   perm = (const int*)d_in[2];
  const float* Wfc  = (const float*)d_in[3];
  const float* bfc  = (const float*)d_in[4];
  const float* b1g  = (const float*)d_in[5];
  const float* b1b  = (const float*)d_in[6];
  const float* b1m  = (const float*)d_in[7];
  const float* b1v  = (const float*)d_in[8];
  const float* Wec  = (const float*)d_in[9];
  const float* b2g  = (const float*)d_in[10];
  const float* b2b  = (const float*)d_in[11];
  const float* b2m  = (const float*)d_in[12];
  const float* b2v  = (const float*)d_in[13];
  const float* Wb   = (const float*)d_in[14];
  const float* bb   = (const float*)d_in[15];
  float* out = (float*)d_out;

  float* ws   = (float*)d_ws;
  float* pts  = ws;
  float* ptsT = pts + (size_t)NB*NPTS*NH;
  float* G1   = ptsT + (size_t)NB*NPTS*NH;
  float* G2   = G1  + (size_t)NB*NPTS*NH;
  float* x2   = G2  + (size_t)NB*NPTS*NH;
  float* sc1w = x2  + (size_t)NB*NPTS;
  int*   nidx = (int*)(sc1w + (size_t)NB*NPTS);

  hipLaunchKernelGGL(k_fc, dim3(NPTS/64, NB), dim3(256), 0, stream,
                     seq1, Wfc, bfc, b1g, b1b, b1m, b1v, Wec, pts, ptsT, G1, G2, x2);
  hipLaunchKernelGGL(k_knn, dim3(NB*NPTS/16), dim3(512), 0, stream,
                     pts, ptsT, x2, nidx);
  hipLaunchKernelGGL(k_score, dim3(NPTS/16, NB), dim3(256), 0, stream,
                     pts, G1, G2, nidx, perm, Wb, b2g, b2b, b2m, b2v, bb, sc1w, out);
  hipLaunchKernelGGL(k_select, dim3(NB), dim3(256), 0, stream,
                     sc1w, seq1, xyz, out);
}

// Round 10
// 1114.913 us; speedup vs baseline: 2.7433x; 2.7433x over previous
//
#include <hip/hip_runtime.h>
#include <math.h>

#define NB 16
#define NH 64
#define NPTS 2048
#define NEIGHS 20
#define KSEL 512
#define EPSV 1e-5f
#define NINF -3.0e38f

typedef unsigned long long ull;

// output layout (floats), reference return order
#define OFF_SEQ 0
#define OFF_VAL (NB*NH*KSEL)            // 524288
#define OFF_IDX (OFF_VAL + NB*KSEL)     // 532480
#define OFF_RET (OFF_IDX + NB*KSEL)     // 540672
#define OFF_XST (OFF_RET + NB*2*NPTS)   // 606208
#define OFF_XO  (OFF_XST + NB*3*KSEL)   // 630784

// exact (val desc, idx asc) total order as one u64: bigger u64 = better
__device__ __forceinline__ ull packkey(float v, int ci) {
  unsigned u = __float_as_uint(v);
  u = (u & 0x80000000u) ? ~u : (u | 0x80000000u);
  return ((ull)u << 32) | (unsigned)(~ci);
}

// K1: pts = relu(bn1(Wfc@seq1 + bfc)), plus x2, G1, G2, and ptsT [b][c][n].
// (unchanged from the passing R8/R9 kernel)
__global__ __launch_bounds__(256) void k_fc(const float* __restrict__ seq1,
                                            const float* __restrict__ Wfc,
                                            const float* __restrict__ bfc,
                                            const float* __restrict__ b1g,
                                            const float* __restrict__ b1b,
                                            const float* __restrict__ b1m,
                                            const float* __restrict__ b1v,
                                            const float* __restrict__ Wec,
                                            float* __restrict__ pts,
                                            float* __restrict__ ptsT,
                                            float* __restrict__ G1,
                                            float* __restrict__ G2,
                                            float* __restrict__ x2) {
  const int b = blockIdx.y, n0 = blockIdx.x * 64;
  const int tid = threadIdx.x, l = tid & 63, w = tid >> 6;
  const int n = n0 + l;
  __shared__ float ptL[64*65];
  const float* sq = seq1 + (size_t)b*NH*NPTS + n;
  float x[64];
  #pragma unroll
  for (int c = 0; c < 64; ++c) x[c] = sq[(size_t)c*NPTS];

  for (int oo = 0; oo < 16; ++oo) {
    const int o = w*16 + oo;
    float acc = 0.f;
    const float* ar = Wfc + o*64;
    #pragma unroll
    for (int c = 0; c < 64; c += 4) {
      float4 a4 = *(const float4*)(ar + c);
      acc = fmaf(a4.x, x[c],   acc);
      acc = fmaf(a4.y, x[c+1], acc);
      acc = fmaf(a4.z, x[c+2], acc);
      acc = fmaf(a4.w, x[c+3], acc);
    }
    float s1 = b1g[o] / sqrtf(b1v[o] + EPSV);
    float y  = (acc + bfc[o] - b1m[o]) * s1 + b1b[o];
    ptL[l*65 + o] = fmaxf(y, 0.f);
  }
  __syncthreads();
  float pt[64];
  #pragma unroll
  for (int c = 0; c < 64; ++c) pt[c] = ptL[l*65 + c];
  if (w == 0) {
    float s2 = 0.f;
    #pragma unroll
    for (int c = 0; c < 64; ++c) s2 = fmaf(pt[c], pt[c], s2);
    x2[(size_t)b*NPTS + n] = s2;
  }
  const size_t base = ((size_t)b*NPTS + n0)*NH;
  for (int t = w*16; t < w*16 + 16; ++t) pts[base + t*64 + l] = ptL[t*65 + l];
  for (int c = w*16; c < w*16 + 16; ++c)
    ptsT[((size_t)b*NH + c)*NPTS + n] = ptL[l*65 + c];
  __syncthreads();

  for (int oo = 0; oo < 16; ++oo) {
    const int o = w*16 + oo;
    const float* w1 = Wec + o*128;
    float a1 = 0.f;
    #pragma unroll
    for (int c = 0; c < 64; c += 4) {
      float4 u = *(const float4*)(w1 + c);
      a1 = fmaf(u.x, pt[c],   a1); a1 = fmaf(u.y, pt[c+1], a1);
      a1 = fmaf(u.z, pt[c+2], a1); a1 = fmaf(u.w, pt[c+3], a1);
    }
    ptL[l*65 + o] = a1;
  }
  __syncthreads();
  for (int t = w*16; t < w*16 + 16; ++t) G1[base + t*64 + l] = ptL[t*65 + l];
  __syncthreads();

  for (int oo = 0; oo < 16; ++oo) {
    const int o = w*16 + oo;
    const float* w2 = Wec + o*128 + 64;
    float a2 = 0.f;
    #pragma unroll
    for (int c = 0; c < 64; c += 4) {
      float4 v = *(const float4*)(w2 + c);
      a2 = fmaf(v.x, pt[c],   a2); a2 = fmaf(v.y, pt[c+1], a2);
      a2 = fmaf(v.z, pt[c+2], a2); a2 = fmaf(v.w, pt[c+3], a2);
    }
    ptL[l*65 + o] = a2;
  }
  __syncthreads();
  for (int t = w*16; t < w*16 + 16; ++t) G2[base + t*64 + l] = ptL[t*65 + l];
}

// ---- K2 helpers ----
#define FMA4(A, s, F) { (A).x = fmaf((s),(F).x,(A).x); (A).y = fmaf((s),(F).y,(A).y); \
                        (A).z = fmaf((s),(F).z,(A).z); (A).w = fmaf((s),(F).w,(A).w); }

// branchless sorted-4 (desc) insert of u64 key (named regs K0..K3)
#define INS4(CAND) { ull c_=(CAND); \
  { bool b_=c_>K0; ull n_=b_?c_:K0; ull o_=K0; c_=b_?o_:c_; K0=n_; } \
  { bool b_=c_>K1; ull n_=b_?c_:K1; ull o_=K1; c_=b_?o_:c_; K1=n_; } \
  { bool b_=c_>K2; ull n_=b_?c_:K2; ull o_=K2; c_=b_?o_:c_; K2=n_; } \
  { bool b_=c_>K3; ull n_=b_?c_:K3; c_=0;       K3=n_; } }

// build sorted-4 for one row's 16 lane-local candidates, dump to LDS
// dump layout [e(4)][row(16)][cell(128)] u64 (lane-consecutive writes)
#define BUILDROW(T0,T1,T2,T3,RI) { \
  ull K0=0,K1=0,K2=0,K3=0; \
  INS4(packkey(fmaf(2.f,(T0).x,-x0.x), cbase+0))   INS4(packkey(fmaf(2.f,(T0).y,-x0.y), cbase+1)) \
  INS4(packkey(fmaf(2.f,(T0).z,-x0.z), cbase+2))   INS4(packkey(fmaf(2.f,(T0).w,-x0.w), cbase+3)) \
  INS4(packkey(fmaf(2.f,(T1).x,-x1.x), cbase+256)) INS4(packkey(fmaf(2.f,(T1).y,-x1.y), cbase+257)) \
  INS4(packkey(fmaf(2.f,(T1).z,-x1.z), cbase+258)) INS4(packkey(fmaf(2.f,(T1).w,-x1.w), cbase+259)) \
  INS4(packkey(fmaf(2.f,(T2).x,-x2q.x), cbase+512)) INS4(packkey(fmaf(2.f,(T2).y,-x2q.y), cbase+513)) \
  INS4(packkey(fmaf(2.f,(T2).z,-x2q.z), cbase+514)) INS4(packkey(fmaf(2.f,(T2).w,-x2q.w), cbase+515)) \
  INS4(packkey(fmaf(2.f,(T3).x,-x3.x), cbase+768)) INS4(packkey(fmaf(2.f,(T3).y,-x3.y), cbase+769)) \
  INS4(packkey(fmaf(2.f,(T3).z,-x3.z), cbase+770)) INS4(packkey(fmaf(2.f,(T3).w,-x3.w), cbase+771)) \
  { int row_ = g*4+(RI), cell_ = h*64+l; \
    dumpS[(0*16+row_)*128 + cell_] = K0; \
    dumpS[(1*16+row_)*128 + cell_] = K1; \
    dumpS[(2*16+row_)*128 + cell_] = K2; \
    dumpS[(3*16+row_)*128 + cell_] = K3; } }

// 20-deep sorted (desc) shift-insert over NAMED u64 regs (no arrays->no scratch)
#define ST(Lk) { bool b_ = c_ > Lk; ull mx_ = b_ ? c_ : Lk; ull mn_ = b_ ? Lk : c_; Lk = mx_; c_ = mn_; }
#define INS20N ST(L00) ST(L01) ST(L02) ST(L03) ST(L04) ST(L05) ST(L06) ST(L07) ST(L08) ST(L09) \
               ST(L10) ST(L11) ST(L12) ST(L13) ST(L14) ST(L15) ST(L16) ST(L17) ST(L18) ST(L19)
#define IDXOF(Lk) ((int)(~(unsigned)(Lk)))

// K2: 8 waves x (4 rows, 16 cols/lane) GEMM (= R8), then exact 3-phase merge:
//  A) quickselect-by-ballot: T = exact 20th-largest of the 128 cell-maxima
//  B) ballot-prefix compaction of the exactly-20 qualifying cells -> 80 survivors
//  C) named-reg ins20 over survivors in level order (K0s,K1s,K2s,K3s)
// Exactness: top-20 entry x => cellmax(x) >= x >= 20th-overall >= T => cell kept.
// Only hazard: a cell with >=5 of the top-20 (5th was never dumped) -> detected
// (max K3 > final L19) -> rare block-wide exact fallback.
__global__ __launch_bounds__(512) void k_knn(const float* __restrict__ pts,
                                             const float* __restrict__ ptsT,
                                             const float* __restrict__ x2,
                                             int* __restrict__ nidx) {
  const int lin = blockIdx.x;
  const int b  = ((lin & 7) << 1) | ((lin >> 3) & 1);  // XCD-local batches
  const int rg = lin >> 4;                              // 0..127
  const int tid = threadIdx.x, w = tid >> 6, l = tid & 63;
  const int g = w >> 1, h = w & 1;     // row group 0..3, col half 0..1
  const int r0 = rg*16;

  __shared__ __align__(16) unsigned char smem[65536 + 4096 + 10240 + 64];
  float* colB0 = (float*)smem;                    // [8192] buf 0
  float* colB1 = (float*)(smem + 32768);          // [8192] buf 1
  ull*   dumpS = (ull*)smem;                      // [4][16][128] overlays colB
  ull*   kbuf  = (ull*)smem;                      // [2048] fallback overlay
  float* rowS  = (float*)(smem + 65536);          // [16][64]
  ull*   survS = (ull*)(smem + 65536 + 4096);     // [16][80]
  int*   flagS = (int*)(smem + 65536 + 4096 + 10240); // [16]

  const float* Tb = ptsT + (size_t)b*NH*NPTS;

  // stage 16 row vectors
  if (tid < 256) {
    int rr = tid >> 4, c4 = (tid & 15) * 4;
    *(float4*)&rowS[rr*64 + c4] =
        *(const float4*)(pts + ((size_t)b*NPTS + r0 + rr)*NH + c4);
  }
  // stage chunk 0
  #pragma unroll
  for (int s = 0; s < 4; ++s) {
    float4 v = *(const float4*)(Tb + (w*4+s)*256 + l*4);
    *(float4*)&colB0[(w*4+s)*256 + l*4] = v;
  }
  __syncthreads();

  float4 A00={0,0,0,0},A01={0,0,0,0},A02={0,0,0,0},A03={0,0,0,0};
  float4 A10={0,0,0,0},A11={0,0,0,0},A12={0,0,0,0},A13={0,0,0,0};
  float4 A20={0,0,0,0},A21={0,0,0,0},A22={0,0,0,0},A23={0,0,0,0};
  float4 A30={0,0,0,0},A31={0,0,0,0},A32={0,0,0,0},A33={0,0,0,0};

  #pragma unroll 1
  for (int t = 0; t < 16; ++t) {
    float4 st0, st1, st2, st3;
    if (t < 15) {   // T14 issue-early
      const float* src = Tb + (size_t)(t+1)*8192 + w*1024 + l*4;
      st0 = *(const float4*)(src);
      st1 = *(const float4*)(src + 256);
      st2 = *(const float4*)(src + 512);
      st3 = *(const float4*)(src + 768);
    }
    const float* cb = ((t & 1) ? colB1 : colB0) + h*1024 + l*4;
    const float* rs = &rowS[(g*4)*64 + t*4];
    #pragma unroll
    for (int k = 0; k < 4; ++k) {
      float4 f0 = *(const float4*)(cb + k*2048);
      float4 f1 = *(const float4*)(cb + k*2048 + 256);
      float4 f2 = *(const float4*)(cb + k*2048 + 512);
      float4 f3 = *(const float4*)(cb + k*2048 + 768);
      float r0k = rs[k], r1k = rs[64 + k], r2k = rs[128 + k], r3k = rs[192 + k];
      FMA4(A00,r0k,f0) FMA4(A01,r0k,f1) FMA4(A02,r0k,f2) FMA4(A03,r0k,f3)
      FMA4(A10,r1k,f0) FMA4(A11,r1k,f1) FMA4(A12,r1k,f2) FMA4(A13,r1k,f3)
      FMA4(A20,r2k,f0) FMA4(A21,r2k,f1) FMA4(A22,r2k,f2) FMA4(A23,r2k,f3)
      FMA4(A30,r3k,f0) FMA4(A31,r3k,f1) FMA4(A32,r3k,f2) FMA4(A33,r3k,f3)
    }
    if (t < 15) {   // write-late
      float* d = ((t & 1) ? colB0 : colB1) + w*1024 + l*4;
      *(float4*)(d)       = st0;
      *(float4*)(d + 256) = st1;
      *(float4*)(d + 512) = st2;
      *(float4*)(d + 768) = st3;
    }
    __syncthreads();
  }
  // colB dead (barrier above) — dumpS overlays it

  const int cbase = h*1024 + l*4;
  const float* x2b = x2 + (size_t)b*NPTS + cbase;
  float4 x0  = *(const float4*)(x2b);
  float4 x1  = *(const float4*)(x2b + 256);
  float4 x2q = *(const float4*)(x2b + 512);
  float4 x3  = *(const float4*)(x2b + 768);

  BUILDROW(A00,A01,A02,A03,0)
  BUILDROW(A10,A11,A12,A13,1)
  BUILDROW(A20,A21,A22,A23,2)
  BUILDROW(A30,A31,A32,A33,3)
  __syncthreads();   // dump visible across waves

  // ---- Phases A+B: per row (whole wave); wave w owns rows w*2, w*2+1 ----
  #pragma unroll 1
  for (int rr = 0; rr < 2; ++rr) {
    const int row = w*2 + rr;
    ull a  = dumpS[(0*16+row)*128 + l];        // cell l K0
    ull bK = dumpS[(0*16+row)*128 + 64 + l];   // cell 64+l K0
    // A: quickselect the exact 20th-largest of 128 K0s via ballots
    ull lo = 0, hi = ~0ull, T = 0; bool done = false;
    for (int it = 0; it < 160 && !done; ++it) {
      bool aA = (a > lo) && (a < hi), aB = (bK > lo) && (bK < hi);
      ull mA = __ballot(aA);
      ull mB = __ballot(aB);
      if (!mA && !mB) break;   // defensive; T should always be active
      ull p;
      if (mA) p = __shfl(a,  (int)__ffsll((long long)mA) - 1, 64);
      else    p = __shfl(bK, (int)__ffsll((long long)mB) - 1, 64);
      int cnt = __popcll(__ballot(a > p)) + __popcll(__ballot(bK > p));
      if (cnt == 19)      { T = p; done = true; }
      else if (cnt > 19)  lo = p;
      else                hi = p;
    }
    if (l == 0) flagS[row] = done ? 0 : 1;
    if (done) {
      // B: exactly 20 cells have K0 >= T; compact their 4 entries -> survS
      bool qa = (a >= T), qb = (bK >= T);
      ull mA = __ballot(qa), mB = __ballot(qb);
      int cntA = __popcll(mA);
      if (qa) {
        int base = __popcll(mA & ((1ull << l) - 1));
        ull k1 = dumpS[(1*16+row)*128 + l];
        ull k2 = dumpS[(2*16+row)*128 + l];
        ull k3 = dumpS[(3*16+row)*128 + l];
        ull* d = &survS[row*80 + base*4];
        d[0] = a; d[1] = k1; d[2] = k2; d[3] = k3;
      }
      if (qb) {
        int base = cntA + __popcll(mB & ((1ull << l) - 1));
        ull k1 = dumpS[(1*16+row)*128 + 64 + l];
        ull k2 = dumpS[(2*16+row)*128 + 64 + l];
        ull k3 = dumpS[(3*16+row)*128 + 64 + l];
        ull* d = &survS[row*80 + base*4];
        d[0] = bK; d[1] = k1; d[2] = k2; d[3] = k3;
      }
    }
  }

  // ---- Phase C: lanes 0..1 do named-reg ins20 over 80 survivors ----
  if (l < 2) {
    const int row = w*2 + l;
    if (flagS[row] == 0) {
      ull L00=0,L01=0,L02=0,L03=0,L04=0,L05=0,L06=0,L07=0,L08=0,L09=0;
      ull L10=0,L11=0,L12=0,L13=0,L14=0,L15=0,L16=0,L17=0,L18=0,L19=0;
      ull m3 = 0;
      #pragma unroll 1
      for (int lvl = 0; lvl < 4; ++lvl) {
        #pragma unroll 1
        for (int c = 0; c < 20; ++c) {
          ull e = survS[row*80 + c*4 + lvl];
          if (lvl == 3) m3 = (e > m3) ? e : m3;
          if (e > L19) { ull c_ = e; INS20N }
        }
      }
      if (m3 > L19) {
        flagS[row] = 1;   // a kept cell's 4th-best beats the 20th: 5th may hide
      } else {
        int* dst = nidx + ((size_t)b*NPTS + r0 + row)*NEIGHS;
        dst[0]=IDXOF(L00);  dst[1]=IDXOF(L01);  dst[2]=IDXOF(L02);  dst[3]=IDXOF(L03);
        dst[4]=IDXOF(L04);  dst[5]=IDXOF(L05);  dst[6]=IDXOF(L06);  dst[7]=IDXOF(L07);
        dst[8]=IDXOF(L08);  dst[9]=IDXOF(L09);  dst[10]=IDXOF(L10); dst[11]=IDXOF(L11);
        dst[12]=IDXOF(L12); dst[13]=IDXOF(L13); dst[14]=IDXOF(L14); dst[15]=IDXOF(L15);
        dst[16]=IDXOF(L16); dst[17]=IDXOF(L17); dst[18]=IDXOF(L18); dst[19]=IDXOF(L19);
      }
    }
  }
  __syncthreads();

  // ---- rare exact fallback: block-wide recompute of flagged rows ----
  #pragma unroll 1
  for (int r = 0; r < 16; ++r) {
    if (flagS[r]) {
      #pragma unroll 1
      for (int col = tid; col < NPTS; col += 512) {
        float acc = 0.f;
        const float* Tc = Tb + col;
        #pragma unroll
        for (int c = 0; c < 64; ++c)
          acc = fmaf(rowS[r*64 + c], Tc[(size_t)c*NPTS], acc);  // identical chain
        kbuf[col] = packkey(fmaf(2.f, acc, -x2[(size_t)b*NPTS + col]), col);
      }
      __syncthreads();
      if (tid == 0) {
        ull L00=0,L01=0,L02=0,L03=0,L04=0,L05=0,L06=0,L07=0,L08=0,L09=0;
        ull L10=0,L11=0,L12=0,L13=0,L14=0,L15=0,L16=0,L17=0,L18=0,L19=0;
        #pragma unroll 1
        for (int col = 0; col < NPTS; ++col) {
          ull e = kbuf[col];
          if (e > L19) { ull c_ = e; INS20N }
        }
        int* dst = nidx + ((size_t)b*NPTS + r0 + r)*NEIGHS;
        dst[0]=IDXOF(L00);  dst[1]=IDXOF(L01);  dst[2]=IDXOF(L02);  dst[3]=IDXOF(L03);
        dst[4]=IDXOF(L04);  dst[5]=IDXOF(L05);  dst[6]=IDXOF(L06);  dst[7]=IDXOF(L07);
        dst[8]=IDXOF(L08);  dst[9]=IDXOF(L09);  dst[10]=IDXOF(L10); dst[11]=IDXOF(L11);
        dst[12]=IDXOF(L12); dst[13]=IDXOF(L13); dst[14]=IDXOF(L14); dst[15]=IDXOF(L15);
        dst[16]=IDXOF(L16); dst[17]=IDXOF(L17); dst[18]=IDXOF(L18); dst[19]=IDXOF(L19);
      }
      __syncthreads();
    }
  }
}

// K3: per-point neighbor max -> X -> v = Wb@X -> sc1/sc2/ret. (unchanged)
__global__ __launch_bounds__(256) void k_score(const float* __restrict__ pts,
    const float* __restrict__ G1, const float* __restrict__ G2,
    const int* __restrict__ nidx, const int* __restrict__ perm,
    const float* __restrict__ Wb,
    const float* __restrict__ b2g, const float* __restrict__ b2b,
    const float* __restrict__ b2m, const float* __restrict__ b2v,
    const float* __restrict__ bb,
    float* __restrict__ sc1w, float* __restrict__ out) {
  const int b = blockIdx.y;
  const int n0 = blockIdx.x * 16;
  const int tid = threadIdx.x, l = tid & 63, w = tid >> 6;
  __shared__ float WbS[64*65];
  for (int i = tid; i < 64*64; i += 256) WbS[(i >> 6)*65 + (i & 63)] = Wb[i];
  __syncthreads();
  const float sc2v = b2g[l] / sqrtf(b2v[l] + EPSV);
  const float mean2 = b2m[l], beta2 = b2b[l];
  const float bbv = bb[0];
  const float* G1b = G1 + (size_t)b*NPTS*NH;
  for (int it = 0; it < 4; ++it) {
    const int n = n0 + it*4 + w;
    const size_t ro = (size_t)b*NPTS*NH + (size_t)n*NH;
    const float base = G2[ro + l] - G1[ro + l];
    const int* nb = nidx + ((size_t)b*NPTS + n)*NEIGHS;
    float mx = NINF;
    #pragma unroll
    for (int k = 0; k < NEIGHS; ++k) {
      int m = nb[k];
      float val = G1b[(size_t)m*NH + l] + base;
      float y = (val - mean2) * sc2v + beta2;
      y = (y >= 0.f) ? y : 0.2f*y;
      mx = fmaxf(mx, y);
    }
    float X = 1.f / (1.f + expf(-mx));
    double v = 0.0;
    #pragma unroll
    for (int d = 0; d < 64; ++d) {
      float xd = __shfl(X, d, 64);
      v += (double)WbS[l*65 + d] * (double)xd;
    }
    float p1 = pts[ro + l];
    int pn = perm[n];
    float p2 = pts[(size_t)b*NPTS*NH + (size_t)pn*NH + l];
    double s1 = (double)p1 * v;
    double s2 = (double)p2 * v;
    #pragma unroll
    for (int off = 32; off > 0; off >>= 1) {
      s1 += __shfl_xor(s1, off, 64);
      s2 += __shfl_xor(s2, off, 64);
    }
    if (l == 0) {
      float r1 = (float)(s1 + (double)bbv);
      float r2 = (float)(s2 + (double)bbv);
      sc1w[(size_t)b*NPTS + n] = r1;
      out[OFF_RET + (size_t)b*2*NPTS + n] = r1;
      out[OFF_RET + (size_t)b*2*NPTS + NPTS + n] = r2;
    }
  }
}

// K4: per-batch exact top-512 via u64 bitonic sort + gathers. (unchanged)
__global__ __launch_bounds__(256) void k_select(const float* __restrict__ sc1w,
    const float* __restrict__ seq1, const float* __restrict__ xyz,
    float* __restrict__ out) {
  const int b = blockIdx.x, tid = threadIdx.x;
  __shared__ unsigned long long keys[NPTS];
  __shared__ float valS[KSEL];
  __shared__ int idxS[KSEL];
  for (int i = tid; i < NPTS; i += 256) {
    float f = sc1w[(size_t)b*NPTS + i];
    unsigned u = __float_as_uint(f);
    u = (u & 0x80000000u) ? ~u : (u | 0x80000000u);
    keys[i] = ((unsigned long long)(~u) << 32) | (unsigned)i;
  }
  __syncthreads();
  for (int k = 2; k <= NPTS; k <<= 1) {
    for (int j = k >> 1; j > 0; j >>= 1) {
      for (int i = tid; i < NPTS; i += 256) {
        int l2 = i ^ j;
        if (l2 > i) {
          unsigned long long a = keys[i], c = keys[l2];
          bool up = ((i & k) == 0);
          if ((a > c) == up) { keys[i] = c; keys[l2] = a; }
        }
      }
      __syncthreads();
    }
  }
  for (int i = tid; i < KSEL; i += 256) {
    unsigned long long key = keys[i];
    int sidx = (int)(key & 0xffffffffULL);
    unsigned u = ~(unsigned)(key >> 32);
    unsigned fb = (u & 0x80000000u) ? (u & 0x7fffffffu) : ~u;
    float f = __uint_as_float(fb);
    float val = 1.f / (1.f + expf(-f));
    valS[i] = val; idxS[i] = sidx;
    out[OFF_VAL + (size_t)b*KSEL + i] = val;
    out[OFF_IDX + (size_t)b*KSEL + i] = (float)sidx;
  }
  __syncthreads();
  for (int t = tid; t < NH*KSEL; t += 256) {
    int c = t >> 9, i = t & (KSEL-1);
    float sv = seq1[((size_t)b*NH + c)*NPTS + idxS[i]];
    out[OFF_SEQ + (((size_t)b*NH + c) << 9) + i] = sv * valS[i];
  }
  for (int t = tid; t < 3*KSEL; t += 256) {
    int c = t >> 9, i = t & (KSEL-1);
    float xv = xyz[((size_t)b*3 + c)*NPTS + idxS[i]];
    out[OFF_XST + (((size_t)b*3 + c) << 9) + i] = xv;
    out[OFF_XO  + (((size_t)b*3 + c) << 9) + i] = xv * valS[i];
  }
}

extern "C" void kernel_launch(void* const* d_in, const int* in_sizes, int n_in,
                              void* d_out, int out_size, void* d_ws, size_t ws_size,
                              hipStream_t stream) {
  const float* xyz  = (const float*)d_in[0];
  const float* seq1 = (const float*)d_in[1];
  const int*   perm = (const int*)d_in[2];
  const float* Wfc  = (const float*)d_in[3];
  const float* bfc  = (const float*)d_in[4];
  const float* b1g  = (const float*)d_in[5];
  const float* b1b  = (const float*)d_in[6];
  const float* b1m  = (const float*)d_in[7];
  const float* b1v  = (const float*)d_in[8];
  const float* Wec  = (const float*)d_in[9];
  const float* b2g  = (const float*)d_in[10];
  const float* b2b  = (const float*)d_in[11];
  const float* b2m  = (const float*)d_in[12];
  const float* b2v  = (const float*)d_in[13];
  const float* Wb   = (const float*)d_in[14];
  const float* bb   = (const float*)d_in[15];
  float* out = (float*)d_out;

  float* ws   = (float*)d_ws;
  float* pts  = ws;
  float* ptsT = pts + (size_t)NB*NPTS*NH;
  float* G1   = ptsT + (size_t)NB*NPTS*NH;
  float* G2   = G1  + (size_t)NB*NPTS*NH;
  float* x2   = G2  + (size_t)NB*NPTS*NH;
  float* sc1w = x2  + (size_t)NB*NPTS;
  int*   nidx = (int*)(sc1w + (size_t)NB*NPTS);

  hipLaunchKernelGGL(k_fc, dim3(NPTS/64, NB), dim3(256), 0, stream,
                     seq1, Wfc, bfc, b1g, b1b, b1m, b1v, Wec, pts, ptsT, G1, G2, x2);
  hipLaunchKernelGGL(k_knn, dim3(NB*NPTS/16), dim3(512), 0, stream,
                     pts, ptsT, x2, nidx);
  hipLaunchKernelGGL(k_score, dim3(NPTS/16, NB), dim3(256), 0, stream,
                     pts, G1, G2, nidx, perm, Wb, b2g, b2b, b2m, b2v, bb, sc1w, out);
  hipLaunchKernelGGL(k_select, dim3(NB), dim3(256), 0, stream,
                     sc1w, seq1, xyz, out);
}

// Round 11
// 1099.270 us; speedup vs baseline: 2.7824x; 1.0142x over previous
//
#include <hip/hip_runtime.h>
#include <math.h>

#define NB 16
#define NH 64
#define NPTS 2048
#define NEIGHS 20
#define KSEL 512
#define EPSV 1e-5f
#define NINF -3.0e38f

typedef unsigned long long ull;

// output layout (floats), reference return order
#define OFF_SEQ 0
#define OFF_VAL (NB*NH*KSEL)            // 524288
#define OFF_IDX (OFF_VAL + NB*KSEL)     // 532480
#define OFF_RET (OFF_IDX + NB*KSEL)     // 540672
#define OFF_XST (OFF_RET + NB*2*NPTS)   // 606208
#define OFF_XO  (OFF_XST + NB*3*KSEL)   // 630784

// exact (val desc, idx asc) total order as one u64: bigger u64 = better
__device__ __forceinline__ ull packkey(float v, int ci) {
  unsigned u = __float_as_uint(v);
  u = (u & 0x80000000u) ? ~u : (u | 0x80000000u);
  return ((ull)u << 32) | (unsigned)(~ci);
}

// K1: pts = relu(bn1(Wfc@seq1 + bfc)), plus x2, G1, G2, and ptsT [b][c][n].
// (bitwise-frozen since R4; do not touch arithmetic)
__global__ __launch_bounds__(256) void k_fc(const float* __restrict__ seq1,
                                            const float* __restrict__ Wfc,
                                            const float* __restrict__ bfc,
                                            const float* __restrict__ b1g,
                                            const float* __restrict__ b1b,
                                            const float* __restrict__ b1m,
                                            const float* __restrict__ b1v,
                                            const float* __restrict__ Wec,
                                            float* __restrict__ pts,
                                            float* __restrict__ ptsT,
                                            float* __restrict__ G1,
                                            float* __restrict__ G2,
                                            float* __restrict__ x2) {
  const int b = blockIdx.y, n0 = blockIdx.x * 64;
  const int tid = threadIdx.x, l = tid & 63, w = tid >> 6;
  const int n = n0 + l;
  __shared__ float ptL[64*65];
  const float* sq = seq1 + (size_t)b*NH*NPTS + n;
  float x[64];
  #pragma unroll
  for (int c = 0; c < 64; ++c) x[c] = sq[(size_t)c*NPTS];

  for (int oo = 0; oo < 16; ++oo) {
    const int o = w*16 + oo;
    float acc = 0.f;
    const float* ar = Wfc + o*64;
    #pragma unroll
    for (int c = 0; c < 64; c += 4) {
      float4 a4 = *(const float4*)(ar + c);
      acc = fmaf(a4.x, x[c],   acc);
      acc = fmaf(a4.y, x[c+1], acc);
      acc = fmaf(a4.z, x[c+2], acc);
      acc = fmaf(a4.w, x[c+3], acc);
    }
    float s1 = b1g[o] / sqrtf(b1v[o] + EPSV);
    float y  = (acc + bfc[o] - b1m[o]) * s1 + b1b[o];
    ptL[l*65 + o] = fmaxf(y, 0.f);
  }
  __syncthreads();
  float pt[64];
  #pragma unroll
  for (int c = 0; c < 64; ++c) pt[c] = ptL[l*65 + c];
  if (w == 0) {
    float s2 = 0.f;
    #pragma unroll
    for (int c = 0; c < 64; ++c) s2 = fmaf(pt[c], pt[c], s2);
    x2[(size_t)b*NPTS + n] = s2;
  }
  const size_t base = ((size_t)b*NPTS + n0)*NH;
  for (int t = w*16; t < w*16 + 16; ++t) pts[base + t*64 + l] = ptL[t*65 + l];
  for (int c = w*16; c < w*16 + 16; ++c)
    ptsT[((size_t)b*NH + c)*NPTS + n] = ptL[l*65 + c];
  __syncthreads();

  for (int oo = 0; oo < 16; ++oo) {
    const int o = w*16 + oo;
    const float* w1 = Wec + o*128;
    float a1 = 0.f;
    #pragma unroll
    for (int c = 0; c < 64; c += 4) {
      float4 u = *(const float4*)(w1 + c);
      a1 = fmaf(u.x, pt[c],   a1); a1 = fmaf(u.y, pt[c+1], a1);
      a1 = fmaf(u.z, pt[c+2], a1); a1 = fmaf(u.w, pt[c+3], a1);
    }
    ptL[l*65 + o] = a1;
  }
  __syncthreads();
  for (int t = w*16; t < w*16 + 16; ++t) G1[base + t*64 + l] = ptL[t*65 + l];
  __syncthreads();

  for (int oo = 0; oo < 16; ++oo) {
    const int o = w*16 + oo;
    const float* w2 = Wec + o*128 + 64;
    float a2 = 0.f;
    #pragma unroll
    for (int c = 0; c < 64; c += 4) {
      float4 v = *(const float4*)(w2 + c);
      a2 = fmaf(v.x, pt[c],   a2); a2 = fmaf(v.y, pt[c+1], a2);
      a2 = fmaf(v.z, pt[c+2], a2); a2 = fmaf(v.w, pt[c+3], a2);
    }
    ptL[l*65 + o] = a2;
  }
  __syncthreads();
  for (int t = w*16; t < w*16 + 16; ++t) G2[base + t*64 + l] = ptL[t*65 + l];
}

// ---- K2 helpers ----
#define FMA4(A, s, F) { (A).x = fmaf((s),(F).x,(A).x); (A).y = fmaf((s),(F).y,(A).y); \
                        (A).z = fmaf((s),(F).z,(A).z); (A).w = fmaf((s),(F).w,(A).w); }

// branchless sorted-4 (desc) insert of u64 key (named regs K0..K3)
#define INS4(CAND) { ull c_=(CAND); \
  { bool b_=c_>K0; ull n_=b_?c_:K0; ull o_=K0; c_=b_?o_:c_; K0=n_; } \
  { bool b_=c_>K1; ull n_=b_?c_:K1; ull o_=K1; c_=b_?o_:c_; K1=n_; } \
  { bool b_=c_>K2; ull n_=b_?c_:K2; ull o_=K2; c_=b_?o_:c_; K2=n_; } \
  { bool b_=c_>K3; ull n_=b_?c_:K3; c_=0;       K3=n_; } }

// build sorted-4 for one row's 16 lane-local candidates; K0,K1 -> LDS dump,
// K2,K3 stay in named registers (passed by ref)
#define BUILDROW(T0,T1,T2,T3,RI,K2S,K3S) { \
  ull K0=0,K1=0,K2=0,K3=0; \
  INS4(packkey(fmaf(2.f,(T0).x,-x0.x), cbase+0))   INS4(packkey(fmaf(2.f,(T0).y,-x0.y), cbase+1)) \
  INS4(packkey(fmaf(2.f,(T0).z,-x0.z), cbase+2))   INS4(packkey(fmaf(2.f,(T0).w,-x0.w), cbase+3)) \
  INS4(packkey(fmaf(2.f,(T1).x,-x1.x), cbase+256)) INS4(packkey(fmaf(2.f,(T1).y,-x1.y), cbase+257)) \
  INS4(packkey(fmaf(2.f,(T1).z,-x1.z), cbase+258)) INS4(packkey(fmaf(2.f,(T1).w,-x1.w), cbase+259)) \
  INS4(packkey(fmaf(2.f,(T2).x,-x2q.x), cbase+512)) INS4(packkey(fmaf(2.f,(T2).y,-x2q.y), cbase+513)) \
  INS4(packkey(fmaf(2.f,(T2).z,-x2q.z), cbase+514)) INS4(packkey(fmaf(2.f,(T2).w,-x2q.w), cbase+515)) \
  INS4(packkey(fmaf(2.f,(T3).x,-x3.x), cbase+768)) INS4(packkey(fmaf(2.f,(T3).y,-x3.y), cbase+769)) \
  INS4(packkey(fmaf(2.f,(T3).z,-x3.z), cbase+770)) INS4(packkey(fmaf(2.f,(T3).w,-x3.w), cbase+771)) \
  { int row_ = g*4+(RI); \
    dump[row_*128 + cell] = K0; \
    dump[2048 + row_*128 + cell] = K1; \
    K2S = K2; K3S = K3; } }

// 20-deep sorted (desc) shift-insert over NAMED u64 regs
#define ST(Lk) { bool b_ = c_ > Lk; ull mx_ = b_ ? c_ : Lk; ull mn_ = b_ ? Lk : c_; Lk = mx_; c_ = mn_; }
#define INS20N ST(L00) ST(L01) ST(L02) ST(L03) ST(L04) ST(L05) ST(L06) ST(L07) ST(L08) ST(L09) \
               ST(L10) ST(L11) ST(L12) ST(L13) ST(L14) ST(L15) ST(L16) ST(L17) ST(L18) ST(L19)
#define IDXOF(Lk) ((int)(~(unsigned)(Lk)))

// phase B': compaction via LDS atomic slots (survivor order irrelevant:
// u64 total order makes ins20 order-independent)
#define PHB(RR,K2S,K3S) { int row_ = g*4+(RR); \
  if (flagS[row_] == 0) { \
    ull K0v = dump[row_*128 + cell]; \
    if (K0v >= TS[row_]) { \
      int slot = atomicAdd(&cntS[row_], 1); \
      if (slot < 20) { \
        ull* d_ = &survS[row_*80 + slot*4]; \
        d_[0] = K0v; d_[1] = dump[2048 + row_*128 + cell]; \
        d_[2] = K2S; d_[3] = K3S; } } } }

// K2: 8 waves x (4 rows, 16 cols/lane) GEMM, k-chunk=2 (colB 32 KB), then:
//  A) ballot-quickselect T = exact 20th-largest of 128 cell-maxima (K0s)
//  B) atomic-slot compaction of the exactly-20 qualifying cells (4 deep)
//  C) named-reg ins20 over the 80 survivors, level-ordered; m3 hazard check
// LDS 46.3 KB (dump overlays dead colB); VGPR capped 128 -> 2 blocks/CU.
__global__ __launch_bounds__(512, 4) void k_knn(const float* __restrict__ pts,
                                                const float* __restrict__ ptsT,
                                                const float* __restrict__ x2,
                                                int* __restrict__ nidx) {
  const int lin = blockIdx.x;
  const int b  = ((lin & 7) << 1) | ((lin >> 3) & 1);  // XCD-local batches
  const int rg = lin >> 4;                              // 0..127
  const int tid = threadIdx.x, w = tid >> 6, l = tid & 63;
  const int g = w >> 1, h = w & 1;     // row group 0..3, col half 0..1
  const int r0 = rg*16;
  const int cell = h*64 + l;           // this lane's cell id (0..127)

  __shared__ __align__(16) unsigned char smem[32768 + 10240 + 4096 + 128 + 64 + 64];
  float* colB  = (float*)smem;                  // [2][2][2048] floats
  ull*   dump  = (ull*)smem;                    // [2][16][128] overlays colB
  ull*   kbuf  = (ull*)smem;                    // [2048] fallback overlay
  ull*   survS = (ull*)(smem + 32768);          // [16][20][4]
  float* rowS  = (float*)(smem + 43008);        // [16][64]
  ull*   TS    = (ull*)(smem + 47104);          // [16]
  int*   cntS  = (int*)(smem + 47232);          // [16]
  int*   flagS = (int*)(smem + 47296);          // [16]

  const float* Tb = ptsT + (size_t)b*NH*NPTS;

  // stage 16 row vectors
  if (tid < 256) {
    int rr = tid >> 4, c4 = (tid & 15) * 4;
    *(float4*)&rowS[rr*64 + c4] =
        *(const float4*)(pts + ((size_t)b*NPTS + r0 + rr)*NH + c4);
  }
  // stage chunk 0 (k-slices 0,1)
  {
    float4 v0 = *(const float4*)(Tb + tid*4);
    float4 v1 = *(const float4*)(Tb + 2048 + tid*4);
    *(float4*)&colB[tid*4]        = v0;
    *(float4*)&colB[2048 + tid*4] = v1;
  }
  __syncthreads();

  float4 A00={0,0,0,0},A01={0,0,0,0},A02={0,0,0,0},A03={0,0,0,0};
  float4 A10={0,0,0,0},A11={0,0,0,0},A12={0,0,0,0},A13={0,0,0,0};
  float4 A20={0,0,0,0},A21={0,0,0,0},A22={0,0,0,0},A23={0,0,0,0};
  float4 A30={0,0,0,0},A31={0,0,0,0},A32={0,0,0,0},A33={0,0,0,0};

  #pragma unroll 1
  for (int t = 0; t < 32; ++t) {
    float4 st0, st1;
    if (t < 31) {   // T14 issue-early (next chunk = k-slices 2t+2, 2t+3)
      const float* src = Tb + (size_t)(t+1)*4096 + tid*4;
      st0 = *(const float4*)(src);
      st1 = *(const float4*)(src + 2048);
    }
    const float* cb = colB + (t & 1)*4096 + h*1024 + l*4;
    const float* rs = &rowS[(g*4)*64 + t*2];
    #pragma unroll
    for (int kk = 0; kk < 2; ++kk) {
      float4 f0 = *(const float4*)(cb + kk*2048);
      float4 f1 = *(const float4*)(cb + kk*2048 + 256);
      float4 f2 = *(const float4*)(cb + kk*2048 + 512);
      float4 f3 = *(const float4*)(cb + kk*2048 + 768);
      float r0k = rs[kk], r1k = rs[64 + kk], r2k = rs[128 + kk], r3k = rs[192 + kk];
      FMA4(A00,r0k,f0) FMA4(A01,r0k,f1) FMA4(A02,r0k,f2) FMA4(A03,r0k,f3)
      FMA4(A10,r1k,f0) FMA4(A11,r1k,f1) FMA4(A12,r1k,f2) FMA4(A13,r1k,f3)
      FMA4(A20,r2k,f0) FMA4(A21,r2k,f1) FMA4(A22,r2k,f2) FMA4(A23,r2k,f3)
      FMA4(A30,r3k,f0) FMA4(A31,r3k,f1) FMA4(A32,r3k,f2) FMA4(A33,r3k,f3)
    }
    if (t < 31) {   // write-late
      float* d = colB + ((t+1) & 1)*4096 + tid*4;
      *(float4*)(d)        = st0;
      *(float4*)(d + 2048) = st1;
    }
    __syncthreads();
  }
  // colB dead (final barrier above) — dump overlays it

  const int cbase = h*1024 + l*4;
  const float* x2b = x2 + (size_t)b*NPTS + cbase;
  float4 x0  = *(const float4*)(x2b);
  float4 x1  = *(const float4*)(x2b + 256);
  float4 x2q = *(const float4*)(x2b + 512);
  float4 x3  = *(const float4*)(x2b + 768);

  ull K2s0,K3s0,K2s1,K3s1,K2s2,K3s2,K2s3,K3s3;
  BUILDROW(A00,A01,A02,A03,0,K2s0,K3s0)
  BUILDROW(A10,A11,A12,A13,1,K2s1,K3s1)
  BUILDROW(A20,A21,A22,A23,2,K2s2,K3s2)
  BUILDROW(A30,A31,A32,A33,3,K2s3,K3s3)
  if (tid < 16) cntS[tid] = 0;
  __syncthreads();   // dump + cntS visible

  // ---- Phase A: wave w -> rows w*2, w*2+1; quickselect T over 128 K0s ----
  #pragma unroll 1
  for (int rr = 0; rr < 2; ++rr) {
    const int row = w*2 + rr;
    ull a  = dump[row*128 + l];
    ull bK = dump[row*128 + 64 + l];
    ull lo = 0, hi = ~0ull, T = 0; bool done = false;
    for (int it = 0; it < 160 && !done; ++it) {
      bool aA = (a > lo) && (a < hi), aB = (bK > lo) && (bK < hi);
      ull mA = __ballot(aA);
      ull mB = __ballot(aB);
      if (!mA && !mB) break;
      ull p;
      if (mA) p = __shfl(a,  (int)__ffsll((long long)mA) - 1, 64);
      else    p = __shfl(bK, (int)__ffsll((long long)mB) - 1, 64);
      int cnt = __popcll(__ballot(a > p)) + __popcll(__ballot(bK > p));
      if (cnt == 19)      { T = p; done = true; }
      else if (cnt > 19)  lo = p;
      else                hi = p;
    }
    if (l == 0) { TS[row] = T; flagS[row] = done ? 0 : 1; }
  }
  __syncthreads();   // TS, flagS visible

  // ---- Phase B': atomic-slot compaction (every lane, its 4 rows) ----
  PHB(0,K2s0,K3s0) PHB(1,K2s1,K3s1) PHB(2,K2s2,K3s2) PHB(3,K2s3,K3s3)
  __syncthreads();

  // ---- Phase C: lanes 0..1 per wave, named-reg ins20 over 80 survivors ----
  if (l < 2) {
    const int row = w*2 + l;
    if (flagS[row] == 0) {
      ull L00=0,L01=0,L02=0,L03=0,L04=0,L05=0,L06=0,L07=0,L08=0,L09=0;
      ull L10=0,L11=0,L12=0,L13=0,L14=0,L15=0,L16=0,L17=0,L18=0,L19=0;
      ull m3 = 0;
      #pragma unroll 1
      for (int lvl = 0; lvl < 4; ++lvl) {
        #pragma unroll 1
        for (int c = 0; c < 20; ++c) {
          ull e = survS[row*80 + c*4 + lvl];
          if (lvl == 3) m3 = (e > m3) ? e : m3;
          if (e > L19) { ull c_ = e; INS20N }
        }
      }
      if (m3 > L19) {
        flagS[row] = 1;   // survivor cell's 4th-best beats 20th: 5th may hide
      } else {
        int* dst = nidx + ((size_t)b*NPTS + r0 + row)*NEIGHS;
        dst[0]=IDXOF(L00);  dst[1]=IDXOF(L01);  dst[2]=IDXOF(L02);  dst[3]=IDXOF(L03);
        dst[4]=IDXOF(L04);  dst[5]=IDXOF(L05);  dst[6]=IDXOF(L06);  dst[7]=IDXOF(L07);
        dst[8]=IDXOF(L08);  dst[9]=IDXOF(L09);  dst[10]=IDXOF(L10); dst[11]=IDXOF(L11);
        dst[12]=IDXOF(L12); dst[13]=IDXOF(L13); dst[14]=IDXOF(L14); dst[15]=IDXOF(L15);
        dst[16]=IDXOF(L16); dst[17]=IDXOF(L17); dst[18]=IDXOF(L18); dst[19]=IDXOF(L19);
      }
    }
  }
  __syncthreads();

  // ---- rare exact fallback: block-wide recompute of flagged rows ----
  #pragma unroll 1
  for (int r = 0; r < 16; ++r) {
    if (flagS[r]) {
      #pragma unroll 1
      for (int col = tid; col < NPTS; col += 512) {
        float acc = 0.f;
        const float* Tc = Tb + col;
        #pragma unroll
        for (int c = 0; c < 64; ++c)
          acc = fmaf(rowS[r*64 + c], Tc[(size_t)c*NPTS], acc);  // identical chain
        kbuf[col] = packkey(fmaf(2.f, acc, -x2[(size_t)b*NPTS + col]), col);
      }
      __syncthreads();
      if (tid == 0) {
        ull L00=0,L01=0,L02=0,L03=0,L04=0,L05=0,L06=0,L07=0,L08=0,L09=0;
        ull L10=0,L11=0,L12=0,L13=0,L14=0,L15=0,L16=0,L17=0,L18=0,L19=0;
        #pragma unroll 1
        for (int col = 0; col < NPTS; ++col) {
          ull e = kbuf[col];
          if (e > L19) { ull c_ = e; INS20N }
        }
        int* dst = nidx + ((size_t)b*NPTS + r0 + r)*NEIGHS;
        dst[0]=IDXOF(L00);  dst[1]=IDXOF(L01);  dst[2]=IDXOF(L02);  dst[3]=IDXOF(L03);
        dst[4]=IDXOF(L04);  dst[5]=IDXOF(L05);  dst[6]=IDXOF(L06);  dst[7]=IDXOF(L07);
        dst[8]=IDXOF(L08);  dst[9]=IDXOF(L09);  dst[10]=IDXOF(L10); dst[11]=IDXOF(L11);
        dst[12]=IDXOF(L12); dst[13]=IDXOF(L13); dst[14]=IDXOF(L14); dst[15]=IDXOF(L15);
        dst[16]=IDXOF(L16); dst[17]=IDXOF(L17); dst[18]=IDXOF(L18); dst[19]=IDXOF(L19);
      }
      __syncthreads();
    }
  }
}

// K3: per-point neighbor max -> X -> v = Wb@X -> sc1/sc2/ret. (frozen)
__global__ __launch_bounds__(256) void k_score(const float* __restrict__ pts,
    const float* __restrict__ G1, const float* __restrict__ G2,
    const int* __restrict__ nidx, const int* __restrict__ perm,
    const float* __restrict__ Wb,
    const float* __restrict__ b2g, const float* __restrict__ b2b,
    const float* __restrict__ b2m, const float* __restrict__ b2v,
    const float* __restrict__ bb,
    float* __restrict__ sc1w, float* __restrict__ out) {
  const int b = blockIdx.y;
  const int n0 = blockIdx.x * 16;
  const int tid = threadIdx.x, l = tid & 63, w = tid >> 6;
  __shared__ float WbS[64*65];
  for (int i = tid; i < 64*64; i += 256) WbS[(i >> 6)*65 + (i & 63)] = Wb[i];
  __syncthreads();
  const float sc2v = b2g[l] / sqrtf(b2v[l] + EPSV);
  const float mean2 = b2m[l], beta2 = b2b[l];
  const float bbv = bb[0];
  const float* G1b = G1 + (size_t)b*NPTS*NH;
  for (int it = 0; it < 4; ++it) {
    const int n = n0 + it*4 + w;
    const size_t ro = (size_t)b*NPTS*NH + (size_t)n*NH;
    const float base = G2[ro + l] - G1[ro + l];
    const int* nb = nidx + ((size_t)b*NPTS + n)*NEIGHS;
    float mx = NINF;
    #pragma unroll
    for (int k = 0; k < NEIGHS; ++k) {
      int m = nb[k];
      float val = G1b[(size_t)m*NH + l] + base;
      float y = (val - mean2) * sc2v + beta2;
      y = (y >= 0.f) ? y : 0.2f*y;
      mx = fmaxf(mx, y);
    }
    float X = 1.f / (1.f + expf(-mx));
    double v = 0.0;
    #pragma unroll
    for (int d = 0; d < 64; ++d) {
      float xd = __shfl(X, d, 64);
      v += (double)WbS[l*65 + d] * (double)xd;
    }
    float p1 = pts[ro + l];
    int pn = perm[n];
    float p2 = pts[(size_t)b*NPTS*NH + (size_t)pn*NH + l];
    double s1 = (double)p1 * v;
    double s2 = (double)p2 * v;
    #pragma unroll
    for (int off = 32; off > 0; off >>= 1) {
      s1 += __shfl_xor(s1, off, 64);
      s2 += __shfl_xor(s2, off, 64);
    }
    if (l == 0) {
      float r1 = (float)(s1 + (double)bbv);
      float r2 = (float)(s2 + (double)bbv);
      sc1w[(size_t)b*NPTS + n] = r1;
      out[OFF_RET + (size_t)b*2*NPTS + n] = r1;
      out[OFF_RET + (size_t)b*2*NPTS + NPTS + n] = r2;
    }
  }
}

// K4: per-batch exact top-512 via u64 bitonic sort + gathers.
// Identical network/comparisons as before; 1024 threads (was 256) — the
// 16-block kernel was barrier-serial, this quarters per-stage iterations.
__global__ __launch_bounds__(1024) void k_select(const float* __restrict__ sc1w,
    const float* __restrict__ seq1, const float* __restrict__ xyz,
    float* __restrict__ out) {
  const int b = blockIdx.x, tid = threadIdx.x;
  __shared__ unsigned long long keys[NPTS];
  __shared__ float valS[KSEL];
  __shared__ int idxS[KSEL];
  for (int i = tid; i < NPTS; i += 1024) {
    float f = sc1w[(size_t)b*NPTS + i];
    unsigned u = __float_as_uint(f);
    u = (u & 0x80000000u) ? ~u : (u | 0x80000000u);
    keys[i] = ((unsigned long long)(~u) << 32) | (unsigned)i;
  }
  __syncthreads();
  for (int k = 2; k <= NPTS; k <<= 1) {
    for (int j = k >> 1; j > 0; j >>= 1) {
      for (int i = tid; i < NPTS; i += 1024) {
        int l2 = i ^ j;
        if (l2 > i) {
          unsigned long long a = keys[i], c = keys[l2];
          bool up = ((i & k) == 0);
          if ((a > c) == up) { keys[i] = c; keys[l2] = a; }
        }
      }
      __syncthreads();
    }
  }
  for (int i = tid; i < KSEL; i += 1024) {
    unsigned long long key = keys[i];
    int sidx = (int)(key & 0xffffffffULL);
    unsigned u = ~(unsigned)(key >> 32);
    unsigned fb = (u & 0x80000000u) ? (u & 0x7fffffffu) : ~u;
    float f = __uint_as_float(fb);
    float val = 1.f / (1.f + expf(-f));
    valS[i] = val; idxS[i] = sidx;
    out[OFF_VAL + (size_t)b*KSEL + i] = val;
    out[OFF_IDX + (size_t)b*KSEL + i] = (float)sidx;
  }
  __syncthreads();
  for (int t = tid; t < NH*KSEL; t += 1024) {
    int c = t >> 9, i = t & (KSEL-1);
    float sv = seq1[((size_t)b*NH + c)*NPTS + idxS[i]];
    out[OFF_SEQ + (((size_t)b*NH + c) << 9) + i] = sv * valS[i];
  }
  for (int t = tid; t < 3*KSEL; t += 1024) {
    int c = t >> 9, i = t & (KSEL-1);
    float xv = xyz[((size_t)b*3 + c)*NPTS + idxS[i]];
    out[OFF_XST + (((size_t)b*3 + c) << 9) + i] = xv;
    out[OFF_XO  + (((size_t)b*3 + c) << 9) + i] = xv * valS[i];
  }
}

extern "C" void kernel_launch(void* const* d_in, const int* in_sizes, int n_in,
                              void* d_out, int out_size, void* d_ws, size_t ws_size,
                              hipStream_t stream) {
  const float* xyz  = (const float*)d_in[0];
  const float* seq1 = (const float*)d_in[1];
  const int*   perm = (const int*)d_in[2];
  const float* Wfc  = (const float*)d_in[3];
  const float* bfc  = (const float*)d_in[4];
  const float* b1g  = (const float*)d_in[5];
  const float* b1b  = (const float*)d_in[6];
  const float* b1m  = (const float*)d_in[7];
  const float* b1v  = (const float*)d_in[8];
  const float* Wec  = (const float*)d_in[9];
  const float* b2g  = (const float*)d_in[10];
  const float* b2b  = (const float*)d_in[11];
  const float* b2m  = (const float*)d_in[12];
  const float* b2v  = (const float*)d_in[13];
  const float* Wb   = (const float*)d_in[14];
  const float* bb   = (const float*)d_in[15];
  float* out = (float*)d_out;

  float* ws   = (float*)d_ws;
  float* pts  = ws;
  float* ptsT = pts + (size_t)NB*NPTS*NH;
  float* G1   = ptsT + (size_t)NB*NPTS*NH;
  float* G2   = G1  + (size_t)NB*NPTS*NH;
  float* x2   = G2  + (size_t)NB*NPTS*NH;
  float* sc1w = x2  + (size_t)NB*NPTS;
  int*   nidx = (int*)(sc1w + (size_t)NB*NPTS);

  hipLaunchKernelGGL(k_fc, dim3(NPTS/64, NB), dim3(256), 0, stream,
                     seq1, Wfc, bfc, b1g, b1b, b1m, b1v, Wec, pts, ptsT, G1, G2, x2);
  hipLaunchKernelGGL(k_knn, dim3(NB*NPTS/16), dim3(512), 0, stream,
                     pts, ptsT, x2, nidx);
  hipLaunchKernelGGL(k_score, dim3(NPTS/16, NB), dim3(256), 0, stream,
                     pts, G1, G2, nidx, perm, Wb, b2g, b2b, b2m, b2v, bb, sc1w, out);
  hipLaunchKernelGGL(k_select, dim3(NB), dim3(1024), 0, stream,
                     sc1w, seq1, xyz, out);
}